// Round 6
// baseline (248.812 us; speedup 1.0000x reference)
//
#include <hip/hip_runtime.h>

// REN forward, B=262144, dims 64, fp32 in/out.
//   du = u@D12^T + bv ; w[i]=tanh(tril(D11,-1)[i,:].w + du[i]) ; y = w@D21^T + u@D22^T + by
//
// R5 resubmit (R5 hit a broker timeout; kernel unchanged so the A/B vs R4's
// 86us @ 19.5% occ / 36% VALU stays clean):
//  - prep kernel pre-converts weights into d_ws (D12 bf16, [D21|D22] bf16,
//    D11^T fp32 tril-masked): kills ~380 f2bf/thread of per-WG reconversion.
//  - u no longer staged in LDS; u MFMA frags load from global once and are
//    reused in phase C (A/B frag layouts share the row/k mapping).
//    LDS 80->48 KB => 3 WG/CU. Only 2 barriers.
//  - recurrence packed as 32x v2f with v_pk_fma_f32 (992 pk-FMA vs 1920 FMA).
//  - Xs (du/w bf16) XOR-swizzled in 16B units by row&7: all frag-width LDS
//    reads/writes sit at the 8-cycle data limit (no excess bank conflict).

#define NQ 64
#define BATCH 262144
#define RT 256
#define NWG (BATCH / RT)

typedef short bf16x8 __attribute__((ext_vector_type(8)));
typedef float f32x4 __attribute__((ext_vector_type(4)));
typedef float v2f __attribute__((ext_vector_type(2)));
typedef unsigned short u16x4 __attribute__((ext_vector_type(4)));
typedef unsigned short u16x8 __attribute__((ext_vector_type(8)));

__device__ __forceinline__ unsigned short f2bf(float f) {
    union { float f; unsigned int u; } v; v.f = f;
    return (unsigned short)((v.u + 0x7fffu + ((v.u >> 16) & 1u)) >> 16);  // RNE
}
__device__ __forceinline__ float bf2f(unsigned short h) {
    union { unsigned int u; float f; } v; v.u = ((unsigned int)h) << 16;
    return v.f;
}
__device__ __forceinline__ float fast_tanh(float x) {
    x = fminf(fmaxf(x, -20.0f), 20.0f);
    float e = __expf(2.0f * x);
    return (e - 1.0f) * __builtin_amdgcn_rcpf(e + 1.0f);
}
__device__ __forceinline__ bf16x8 pack8(float4 a, float4 b) {
    bf16x8 r;
    r[0] = (short)f2bf(a.x); r[1] = (short)f2bf(a.y);
    r[2] = (short)f2bf(a.z); r[3] = (short)f2bf(a.w);
    r[4] = (short)f2bf(b.x); r[5] = (short)f2bf(b.y);
    r[6] = (short)f2bf(b.z); r[7] = (short)f2bf(b.w);
    return r;
}
// Xs[row][col], row<256, col<64 shorts; 16B units XORed by row&7.
__device__ __forceinline__ int sidx(int row, int col) {
    return row * 64 + ((((col >> 3) ^ (row & 7))) << 3) + (col & 7);
}

// ======================= prep: weight conversion =========================
// ws layout (bytes): [0,8K) D12 bf16 [i][k]; [8K,24K) Dcat bf16 [i][128k]
// (=[D21|D22]); [24K,40K) D11T fp32 [j][i], zero at i<=j.
__global__ __launch_bounds__(256) void ren_prep(
    const float* __restrict__ D11, const float* __restrict__ D12,
    const float* __restrict__ D21, const float* __restrict__ D22,
    unsigned short* __restrict__ ws)
{
    const int idx = blockIdx.x * 256 + threadIdx.x;      // 64 blocks -> 16384
    if (idx < 4096) {
        ws[idx] = f2bf(D12[idx]);
    } else if (idx < 12288) {
        const int e = idx - 4096;
        const int i = e >> 7, k = e & 127;
        float v = (k < NQ) ? D21[i * NQ + k] : D22[i * NQ + (k - NQ)];
        ws[idx] = f2bf(v);
    } else {
        const int e = idx - 12288;
        const int j = e >> 6, i = e & 63;
        float* D11T = reinterpret_cast<float*>(ws + 12288);
        D11T[e] = (i > j) ? D11[i * NQ + j] : 0.0f;
    }
}

// ============================ main kernel ================================
__global__ __launch_bounds__(256, 3) void ren_fused(
    const float* __restrict__ u,
    const unsigned short* __restrict__ wsu,   // D12b @0, Dcatb @4096 (shorts)
    const float* __restrict__ bv,
    const float* __restrict__ by,
    float* __restrict__ out)
{
    __shared__ __align__(16) unsigned short Xs[RT * NQ];  // 32 KB du/w bf16
    __shared__ __align__(16) float D11Ts[NQ * NQ];        // 16 KB

    const unsigned short* D12b  = wsu;
    const unsigned short* Dcatb = wsu + 4096;
    const float* D11Tg = reinterpret_cast<const float*>(wsu + 12288);

    const int tid  = threadIdx.x;
    const int lane = tid & 63;
    const int wv   = tid >> 6;
    const int ln15 = lane & 15;
    const int kg   = lane >> 4;          // 0..3
    const int wrow0 = wv * 64;
    const size_t R0 = (size_t)blockIdx.x * RT;

    // ---- stage D11T (coalesced global->LDS, 4 float4/thread) ----
#pragma unroll
    for (int q = 0; q < 4; ++q) {
        const int e = tid * 16 + q * 4;
        *reinterpret_cast<float4*>(&D11Ts[e]) =
            *reinterpret_cast<const float4*>(D11Tg + e);
    }

    // ---- u fragments: rows wrow0+r*16+ln15, k = kt*32+kg*8; load once,
    //      used as B-frags (phase A) and A-frags (phase C) ----
    bf16x8 uf[4][2];
#pragma unroll
    for (int r = 0; r < 4; ++r)
#pragma unroll
        for (int kt = 0; kt < 2; ++kt) {
            const float* p = u + (R0 + wrow0 + r * 16 + ln15) * NQ + kt * 32 + kg * 8;
            uf[r][kt] = pack8(*reinterpret_cast<const float4*>(p),
                              *reinterpret_cast<const float4*>(p + 4));
        }

    // ================= Phase A: du^T = D12 @ u^T (MFMA) ====================
    {
        f32x4 acc[4][4];                                 // [mt=i][nt=row]
#pragma unroll
        for (int mt = 0; mt < 4; ++mt) {
            float4 b4 = *reinterpret_cast<const float4*>(bv + mt * 16 + kg * 4);
#pragma unroll
            for (int nt = 0; nt < 4; ++nt)
                acc[mt][nt] = (f32x4){b4.x, b4.y, b4.z, b4.w};
        }
#pragma unroll
        for (int kt = 0; kt < 2; ++kt) {
#pragma unroll
            for (int mt = 0; mt < 4; ++mt) {
                bf16x8 af = *reinterpret_cast<const bf16x8*>(
                    D12b + (mt * 16 + ln15) * NQ + kt * 32 + kg * 8);
#pragma unroll
                for (int nt = 0; nt < 4; ++nt)
                    acc[mt][nt] = __builtin_amdgcn_mfma_f32_16x16x32_bf16(
                        af, uf[nt][kt], acc[mt][nt], 0, 0, 0);
            }
        }
        // du -> Xs (bf16). C-layout: i = mt*16+kg*4+reg, row = wrow0+nt*16+ln15.
#pragma unroll
        for (int mt = 0; mt < 4; ++mt)
#pragma unroll
            for (int nt = 0; nt < 4; ++nt) {
                const int row = wrow0 + nt * 16 + ln15;
                u16x4 h = { f2bf(acc[mt][nt][0]), f2bf(acc[mt][nt][1]),
                            f2bf(acc[mt][nt][2]), f2bf(acc[mt][nt][3]) };
                *reinterpret_cast<u16x4*>(&Xs[sidx(row, mt * 16 + kg * 4)]) = h;
            }
    }
    __syncthreads();

    // ================= Phase B: packed triangular recurrence ===============
    {
        const int r = tid;
        v2f a2[32];
#pragma unroll
        for (int c = 0; c < 8; ++c) {
            u16x8 h = *reinterpret_cast<const u16x8*>(&Xs[sidx(r, c * 8)]);
#pragma unroll
            for (int e = 0; e < 4; ++e)
                a2[c * 4 + e] = (v2f){bf2f(h[2 * e]), bf2f(h[2 * e + 1])};
        }
#pragma unroll
        for (int j = 0; j < NQ; ++j) {
            const float wj = fast_tanh(a2[j >> 1][j & 1]);
            a2[j >> 1][j & 1] = wj;
            const v2f w2 = (v2f){wj, wj};
            const int p0 = (j + 1) >> 1;                 // D11T zeros cover i<=j
#pragma unroll
            for (int c = p0 >> 1; c < 16; ++c) {         // quad granularity
                float4 d = *reinterpret_cast<const float4*>(&D11Ts[j * NQ + c * 4]);
                a2[c * 2 + 0] = __builtin_elementwise_fma((v2f){d.x, d.y}, w2, a2[c * 2 + 0]);
                a2[c * 2 + 1] = __builtin_elementwise_fma((v2f){d.z, d.w}, w2, a2[c * 2 + 1]);
            }
        }
        // w -> Xs (bf16)
#pragma unroll
        for (int c = 0; c < 8; ++c) {
            u16x8 h;
#pragma unroll
            for (int e = 0; e < 4; ++e) {
                h[2 * e]     = f2bf(a2[c * 4 + e].x);
                h[2 * e + 1] = f2bf(a2[c * 4 + e].y);
            }
            *reinterpret_cast<u16x8*>(&Xs[sidx(r, c * 8)]) = h;
        }
    }
    __syncthreads();

    // ================= Phase C: y = [w|u] @ [D21|D22]^T (MFMA) =============
    {
        f32x4 yac[4][4];                                 // [mt=row][nt=i]
#pragma unroll
        for (int nt = 0; nt < 4; ++nt) {
            const float b = by[nt * 16 + ln15];
#pragma unroll
            for (int mt = 0; mt < 4; ++mt)
                yac[mt][nt] = (f32x4){b, b, b, b};
        }
        bf16x8 afw[4][2];
#pragma unroll
        for (int mt = 0; mt < 4; ++mt)
#pragma unroll
            for (int kt = 0; kt < 2; ++kt)
                afw[mt][kt] = *reinterpret_cast<const bf16x8*>(
                    &Xs[sidx(wrow0 + mt * 16 + ln15, kt * 32 + kg * 8)]);
#pragma unroll
        for (int kt = 0; kt < 4; ++kt) {
#pragma unroll
            for (int nt = 0; nt < 4; ++nt) {
                bf16x8 bf = *reinterpret_cast<const bf16x8*>(
                    Dcatb + (nt * 16 + ln15) * 128 + kt * 32 + kg * 8);
#pragma unroll
                for (int mt = 0; mt < 4; ++mt) {
                    bf16x8 af = (kt < 2) ? afw[mt][kt] : uf[mt][kt - 2];
                    yac[mt][nt] = __builtin_amdgcn_mfma_f32_16x16x32_bf16(
                        af, bf, yac[mt][nt], 0, 0, 0);
                }
            }
        }
        // store y fp32: row = R0+wrow0+mt*16+kg*4+reg, col = nt*16+ln15
#pragma unroll
        for (int mt = 0; mt < 4; ++mt) {
            const size_t row = R0 + wrow0 + mt * 16 + kg * 4;
#pragma unroll
            for (int nt = 0; nt < 4; ++nt) {
                const int colI = nt * 16 + ln15;
                out[(row + 0) * NQ + colI] = yac[mt][nt][0];
                out[(row + 1) * NQ + colI] = yac[mt][nt][1];
                out[(row + 2) * NQ + colI] = yac[mt][nt][2];
                out[(row + 3) * NQ + colI] = yac[mt][nt][3];
            }
        }
    }
}

extern "C" void kernel_launch(void* const* d_in, const int* in_sizes, int n_in,
                              void* d_out, int out_size, void* d_ws, size_t ws_size,
                              hipStream_t stream) {
    // setup_inputs order: t(1), xi, u, D11, D12, D21, D22, bv, by
    const float* u   = (const float*)d_in[2];
    const float* D11 = (const float*)d_in[3];
    const float* D12 = (const float*)d_in[4];
    const float* D21 = (const float*)d_in[5];
    const float* D22 = (const float*)d_in[6];
    const float* bv  = (const float*)d_in[7];
    const float* by  = (const float*)d_in[8];
    float* out = (float*)d_out;
    unsigned short* ws = (unsigned short*)d_ws;

    ren_prep<<<64, 256, 0, stream>>>(D11, D12, D21, D22, ws);
    ren_fused<<<NWG, 256, 0, stream>>>(u, ws, bv, by, out);
}

// Round 8
// 247.419 us; speedup vs baseline: 1.0056x; 1.0056x over previous
//
#include <hip/hip_runtime.h>

// REN forward, B=262144, dims 64, fp32 in/out.
//   du = u@D12^T + bv ; w[i]=tanh(tril(D11,-1)[i,:].w + du[i]) ; y = w@D21^T + u@D22^T + by
//
// R8 = R7 resubmit (broker timeout; unchanged for clean A/B vs R6):
// R5 + amdgpu_waves_per_eu(3,3). R6 showed the allocator targeted 6 waves/EU
// (VGPR=84 = 512/6) and spilled ~520B/thread (WRITE 202MB vs 66MB output)
// even though 48KB LDS caps the CU at 3 WG = 3 waves/EU -- the spill bought
// nothing. Pinning waves/EU to exactly 3 gives the allocator its real budget
// (~168 VGPRs) so the ~150-reg working set (uf frags live A->C, a2[32]
// recurrence state) stays in registers.
//  - prep kernel pre-converts weights into d_ws (D12 bf16, [D21|D22] bf16,
//    D11^T fp32 tril-masked).
//  - u MFMA frags load from global once, reused in phase C.
//  - recurrence packed as 32x v2f (v_pk_fma_f32).
//  - Xs XOR-swizzled in 16B units by row&7 (conflict-free frag access).

#define NQ 64
#define BATCH 262144
#define RT 256
#define NWG (BATCH / RT)

typedef short bf16x8 __attribute__((ext_vector_type(8)));
typedef float f32x4 __attribute__((ext_vector_type(4)));
typedef float v2f __attribute__((ext_vector_type(2)));
typedef unsigned short u16x4 __attribute__((ext_vector_type(4)));
typedef unsigned short u16x8 __attribute__((ext_vector_type(8)));

__device__ __forceinline__ unsigned short f2bf(float f) {
    union { float f; unsigned int u; } v; v.f = f;
    return (unsigned short)((v.u + 0x7fffu + ((v.u >> 16) & 1u)) >> 16);  // RNE
}
__device__ __forceinline__ float bf2f(unsigned short h) {
    union { unsigned int u; float f; } v; v.u = ((unsigned int)h) << 16;
    return v.f;
}
__device__ __forceinline__ float fast_tanh(float x) {
    x = fminf(fmaxf(x, -20.0f), 20.0f);
    float e = __expf(2.0f * x);
    return (e - 1.0f) * __builtin_amdgcn_rcpf(e + 1.0f);
}
__device__ __forceinline__ bf16x8 pack8(float4 a, float4 b) {
    bf16x8 r;
    r[0] = (short)f2bf(a.x); r[1] = (short)f2bf(a.y);
    r[2] = (short)f2bf(a.z); r[3] = (short)f2bf(a.w);
    r[4] = (short)f2bf(b.x); r[5] = (short)f2bf(b.y);
    r[6] = (short)f2bf(b.z); r[7] = (short)f2bf(b.w);
    return r;
}
// Xs[row][col], row<256, col<64 shorts; 16B units XORed by row&7.
__device__ __forceinline__ int sidx(int row, int col) {
    return row * 64 + ((((col >> 3) ^ (row & 7))) << 3) + (col & 7);
}

// ======================= prep: weight conversion =========================
// ws layout (shorts): [0,4096) D12 bf16 [i][k]; [4096,12288) Dcat bf16
// [i][128] (=[D21|D22]); [12288,...) D11T fp32 [j][i], zero at i<=j.
__global__ __launch_bounds__(256) void ren_prep(
    const float* __restrict__ D11, const float* __restrict__ D12,
    const float* __restrict__ D21, const float* __restrict__ D22,
    unsigned short* __restrict__ ws)
{
    const int idx = blockIdx.x * 256 + threadIdx.x;      // 64 blocks -> 16384
    if (idx < 4096) {
        ws[idx] = f2bf(D12[idx]);
    } else if (idx < 12288) {
        const int e = idx - 4096;
        const int i = e >> 7, k = e & 127;
        float v = (k < NQ) ? D21[i * NQ + k] : D22[i * NQ + (k - NQ)];
        ws[idx] = f2bf(v);
    } else {
        const int e = idx - 12288;
        const int j = e >> 6, i = e & 63;
        float* D11T = reinterpret_cast<float*>(ws + 12288);
        D11T[e] = (i > j) ? D11[i * NQ + j] : 0.0f;
    }
}

// ============================ main kernel ================================
__global__ __launch_bounds__(256)
__attribute__((amdgpu_waves_per_eu(3, 3)))
void ren_fused(
    const float* __restrict__ u,
    const unsigned short* __restrict__ wsu,   // D12b @0, Dcatb @4096 (shorts)
    const float* __restrict__ bv,
    const float* __restrict__ by,
    float* __restrict__ out)
{
    __shared__ __align__(16) unsigned short Xs[RT * NQ];  // 32 KB du/w bf16
    __shared__ __align__(16) float D11Ts[NQ * NQ];        // 16 KB

    const unsigned short* D12b  = wsu;
    const unsigned short* Dcatb = wsu + 4096;
    const float* D11Tg = reinterpret_cast<const float*>(wsu + 12288);

    const int tid  = threadIdx.x;
    const int lane = tid & 63;
    const int wv   = tid >> 6;
    const int ln15 = lane & 15;
    const int kg   = lane >> 4;          // 0..3
    const int wrow0 = wv * 64;
    const size_t R0 = (size_t)blockIdx.x * RT;

    // ---- stage D11T (coalesced global->LDS, 4 float4/thread) ----
#pragma unroll
    for (int q = 0; q < 4; ++q) {
        const int e = tid * 16 + q * 4;
        *reinterpret_cast<float4*>(&D11Ts[e]) =
            *reinterpret_cast<const float4*>(D11Tg + e);
    }

    // ---- u fragments: rows wrow0+r*16+ln15, k = kt*32+kg*8; load once,
    //      used as B-frags (phase A) and A-frags (phase C) ----
    bf16x8 uf[4][2];
#pragma unroll
    for (int r = 0; r < 4; ++r)
#pragma unroll
        for (int kt = 0; kt < 2; ++kt) {
            const float* p = u + (R0 + wrow0 + r * 16 + ln15) * NQ + kt * 32 + kg * 8;
            uf[r][kt] = pack8(*reinterpret_cast<const float4*>(p),
                              *reinterpret_cast<const float4*>(p + 4));
        }

    // ================= Phase A: du^T = D12 @ u^T (MFMA) ====================
    {
        f32x4 acc[4][4];                                 // [mt=i][nt=row]
#pragma unroll
        for (int mt = 0; mt < 4; ++mt) {
            float4 b4 = *reinterpret_cast<const float4*>(bv + mt * 16 + kg * 4);
#pragma unroll
            for (int nt = 0; nt < 4; ++nt)
                acc[mt][nt] = (f32x4){b4.x, b4.y, b4.z, b4.w};
        }
#pragma unroll
        for (int kt = 0; kt < 2; ++kt) {
#pragma unroll
            for (int mt = 0; mt < 4; ++mt) {
                bf16x8 af = *reinterpret_cast<const bf16x8*>(
                    D12b + (mt * 16 + ln15) * NQ + kt * 32 + kg * 8);
#pragma unroll
                for (int nt = 0; nt < 4; ++nt)
                    acc[mt][nt] = __builtin_amdgcn_mfma_f32_16x16x32_bf16(
                        af, uf[nt][kt], acc[mt][nt], 0, 0, 0);
            }
        }
        // du -> Xs (bf16). C-layout: i = mt*16+kg*4+reg, row = wrow0+nt*16+ln15.
#pragma unroll
        for (int mt = 0; mt < 4; ++mt)
#pragma unroll
            for (int nt = 0; nt < 4; ++nt) {
                const int row = wrow0 + nt * 16 + ln15;
                u16x4 h = { f2bf(acc[mt][nt][0]), f2bf(acc[mt][nt][1]),
                            f2bf(acc[mt][nt][2]), f2bf(acc[mt][nt][3]) };
                *reinterpret_cast<u16x4*>(&Xs[sidx(row, mt * 16 + kg * 4)]) = h;
            }
    }
    __syncthreads();

    // ================= Phase B: packed triangular recurrence ===============
    {
        const int r = tid;
        v2f a2[32];
#pragma unroll
        for (int c = 0; c < 8; ++c) {
            u16x8 h = *reinterpret_cast<const u16x8*>(&Xs[sidx(r, c * 8)]);
#pragma unroll
            for (int e = 0; e < 4; ++e)
                a2[c * 4 + e] = (v2f){bf2f(h[2 * e]), bf2f(h[2 * e + 1])};
        }
#pragma unroll
        for (int j = 0; j < NQ; ++j) {
            const float wj = fast_tanh(a2[j >> 1][j & 1]);
            a2[j >> 1][j & 1] = wj;
            const v2f w2 = (v2f){wj, wj};
            const int p0 = (j + 1) >> 1;                 // D11T zeros cover i<=j
#pragma unroll
            for (int c = p0 >> 1; c < 16; ++c) {         // quad granularity
                float4 d = *reinterpret_cast<const float4*>(&D11Ts[j * NQ + c * 4]);
                a2[c * 2 + 0] = __builtin_elementwise_fma((v2f){d.x, d.y}, w2, a2[c * 2 + 0]);
                a2[c * 2 + 1] = __builtin_elementwise_fma((v2f){d.z, d.w}, w2, a2[c * 2 + 1]);
            }
        }
        // w -> Xs (bf16)
#pragma unroll
        for (int c = 0; c < 8; ++c) {
            u16x8 h;
#pragma unroll
            for (int e = 0; e < 4; ++e) {
                h[2 * e]     = f2bf(a2[c * 4 + e].x);
                h[2 * e + 1] = f2bf(a2[c * 4 + e].y);
            }
            *reinterpret_cast<u16x8*>(&Xs[sidx(r, c * 8)]) = h;
        }
    }
    __syncthreads();

    // ================= Phase C: y = [w|u] @ [D21|D22]^T (MFMA) =============
    {
        f32x4 yac[4][4];                                 // [mt=row][nt=i]
#pragma unroll
        for (int nt = 0; nt < 4; ++nt) {
            const float b = by[nt * 16 + ln15];
#pragma unroll
            for (int mt = 0; mt < 4; ++mt)
                yac[mt][nt] = (f32x4){b, b, b, b};
        }
        bf16x8 afw[4][2];
#pragma unroll
        for (int mt = 0; mt < 4; ++mt)
#pragma unroll
            for (int kt = 0; kt < 2; ++kt)
                afw[mt][kt] = *reinterpret_cast<const bf16x8*>(
                    &Xs[sidx(wrow0 + mt * 16 + ln15, kt * 32 + kg * 8)]);
#pragma unroll
        for (int kt = 0; kt < 4; ++kt) {
#pragma unroll
            for (int nt = 0; nt < 4; ++nt) {
                bf16x8 bf = *reinterpret_cast<const bf16x8*>(
                    Dcatb + (nt * 16 + ln15) * 128 + kt * 32 + kg * 8);
#pragma unroll
                for (int mt = 0; mt < 4; ++mt) {
                    bf16x8 af = (kt < 2) ? afw[mt][kt] : uf[mt][kt - 2];
                    yac[mt][nt] = __builtin_amdgcn_mfma_f32_16x16x32_bf16(
                        af, bf, yac[mt][nt], 0, 0, 0);
                }
            }
        }
        // store y fp32: row = R0+wrow0+mt*16+kg*4+reg, col = nt*16+ln15
#pragma unroll
        for (int mt = 0; mt < 4; ++mt) {
            const size_t row = R0 + wrow0 + mt * 16 + kg * 4;
#pragma unroll
            for (int nt = 0; nt < 4; ++nt) {
                const int colI = nt * 16 + ln15;
                out[(row + 0) * NQ + colI] = yac[mt][nt][0];
                out[(row + 1) * NQ + colI] = yac[mt][nt][1];
                out[(row + 2) * NQ + colI] = yac[mt][nt][2];
                out[(row + 3) * NQ + colI] = yac[mt][nt][3];
            }
        }
    }
}

extern "C" void kernel_launch(void* const* d_in, const int* in_sizes, int n_in,
                              void* d_out, int out_size, void* d_ws, size_t ws_size,
                              hipStream_t stream) {
    // setup_inputs order: t(1), xi, u, D11, D12, D21, D22, bv, by
    const float* u   = (const float*)d_in[2];
    const float* D11 = (const float*)d_in[3];
    const float* D12 = (const float*)d_in[4];
    const float* D21 = (const float*)d_in[5];
    const float* D22 = (const float*)d_in[6];
    const float* bv  = (const float*)d_in[7];
    const float* by  = (const float*)d_in[8];
    float* out = (float*)d_out;
    unsigned short* ws = (unsigned short*)d_ws;

    ren_prep<<<64, 256, 0, stream>>>(D11, D12, D21, D22, ws);
    ren_fused<<<NWG, 256, 0, stream>>>(u, ws, bv, by, out);
}